// Round 10
// baseline (233.519 us; speedup 1.0000x reference)
//
#include <hip/hip_runtime.h>

// ---------------------------------------------------------------------------
// CovariateAttention: out = MHA_causal(rope(x@Wq^T), rope(x@Wk^T), x@Wv^T) @ Wo^T
// B=2, S=2048, E=d_attn=1024, H=16, hd=64. All GEMM-shaped work in bf16 MFMA.
// 4 launches: cvt -> gemm0(QKV + fused RoPE, BN=64) -> attnk(8-wave) -> gemm2.
// r20: attnk reverted to r17-exact (kv-half split r19 measured -1.9us).
//      gemm_bt: k-major LDS staging permutation kills an 8-WAY bank conflict
//      on every fragment read (see gemm header) — the 4.7M-conflict constant.
// ---------------------------------------------------------------------------

typedef float  f32x4  __attribute__((ext_vector_type(4)));
typedef short  short8 __attribute__((ext_vector_type(8)));

#define MFMA16(a,b,c) __builtin_amdgcn_mfma_f32_16x16x32_bf16((a),(b),(c),0,0,0)
// async global->LDS DMA, 16B/lane; LDS dest = wave-uniform base + lane*16
#define GLD_LDS16(g, l)                                                        \
  __builtin_amdgcn_global_load_lds(                                            \
      (const __attribute__((address_space(1))) unsigned int*)(g),              \
      (__attribute__((address_space(3))) unsigned int*)(l), 16, 0, 0)

__device__ __forceinline__ unsigned short f2bf(float f) {
  unsigned int x = __float_as_uint(f);
  x += 0x7fffu + ((x >> 16) & 1u);          // RNE
  return (unsigned short)(x >> 16);
}
__device__ __forceinline__ float bf2f(unsigned short u) {
  return __uint_as_float(((unsigned int)u) << 16);
}
// packed f32x2 -> bf16x2 (RNE). No builtin on gfx950 (m240) -> inline asm.
__device__ __forceinline__ unsigned int cvtpk_bf16(float lo, float hi) {
  unsigned int r;
  asm("v_cvt_pk_bf16_f32 %0, %1, %2" : "=v"(r) : "v"(lo), "v"(hi));
  return r;
}

// ---------------------------------------------------------------------------
// Kernel 1: convert x (4M fp32) + Wq,Wk,Wv,Wo (1M each) to bf16 (contiguous).
// ---------------------------------------------------------------------------
__global__ __launch_bounds__(256) void cvt_all(const float* __restrict__ x,
                                               const float* __restrict__ wq,
                                               const float* __restrict__ wk,
                                               const float* __restrict__ wv,
                                               const float* __restrict__ wo,
                                               ushort* __restrict__ dst) {
  const int i = blockIdx.x * 256 + threadIdx.x;      // [0, 2M)
  const float* src;
  int off;
  if (i < 1048576) { src = x; off = i; }
  else {
    const int j = i - 1048576;
    const int wsel = j >> 18;
    off = j & 262143;
    src = (wsel == 0) ? wq : (wsel == 1) ? wk : (wsel == 2) ? wv : wo;
  }
  const float4 v = ((const float4*)src)[off];
  ushort4 o = make_ushort4(f2bf(v.x), f2bf(v.y), f2bf(v.z), f2bf(v.w));
  ((ushort4*)dst)[i] = o;
}

// ---------------------------------------------------------------------------
// GEMM (r9-exact K-loop structure, FROZEN; r20 changes ONLY the LDS data
// layout). C[m,n] = sum_k A[m,k]*B[n,k]. BM x BN tile, 256 thr = 4 waves
// (2x2), wave tile (BM/2) x (BN/2). BK=64 staged as TWO stride-32 panels via
// global_load_lds width=16; 2-barrier K-loop.
//
// r20 BANK-CONFLICT FIX: the old row-major [16rows][4x16B] window layout put
// fragment reads at byte row*64 + quad*16 -> bank (ln*16+quad*4)%32 -> only
// 2 distinct banks per 16-lane group = 8-WAY conflict (m136: 2.94x). That is
// the 4.7M SQ_LDS_BANK_CONFLICT seen on every gemm dispatch, and ~100Kcy/CU
// of LDS-port occupancy (vs 113Kcy kernel) — the shared resource that made
// r10/r15 pipelining attempts null. Since global_load_lds writes linearly
// (base+lane*16, rule #21), we permute the per-lane GLOBAL source instead:
// lane l sources (row = l&15, kchunk = l>>4), so the linear dest lands
// k-chunk-major [4][16] per 16-row window. Reads become
// window*1024 + quad*256 + ln*16 -> bank ln*4%32 -> 2-way = free (m136).
// Same global address set per wave (16 rows x 64B) -> coalescing unchanged.
//
// MODE 0 (BM=128, BN=64): fused QKV, N=3072, 1536 blocks = 6/CU. Q/K get
//   RoPE in the epilogue. Q scaled by attn_scale*log2e. V -> [bh][d][s].
// MODE 2 (BM=64, BN=64): fp32 out-proj, 1024 blocks = 4/CU.
// ---------------------------------------------------------------------------
template<int MODE, int BN, int BM>
__global__ __launch_bounds__(256) void gemm_bt(const ushort* __restrict__ A,
                                               const ushort* __restrict__ B,
                                               void* __restrict__ Cv,
                                               int K) {
  constexpr int NI = BN / 32;               // n-frags per wave
  constexpr int MI = BM / 32;               // m-frags per wave
  constexpr int AI = BM / 64;               // A staging instrs per wave/panel
  constexpr int BI = BN / 64;               // B staging instrs per wave/panel
  __shared__ __align__(16) short As0[BM * 32];
  __shared__ __align__(16) short As1[BM * 32];
  __shared__ __align__(16) short Bs0[BN * 32];
  __shared__ __align__(16) short Bs1[BN * 32];
  const int tid  = threadIdx.x;
  const int lane = tid & 63, w = tid >> 6;
  const int ln   = lane & 15, quad = lane >> 4;
  const int wm   = w >> 1, wn = w & 1;
  const int m0 = blockIdx.y * BM, n0 = blockIdx.x * BN;

  // r20: k-major source permutation (see header)
  const int srow = lane & 15;               // 0..15 (row within window)
  const int schk = (lane >> 4) * 8;         // 0,8,16,24 (k-chunk, shorts)
  const int arow = w * (16 * AI);
  const int brow = w * (16 * BI);
  const ushort* Ag0 = A + (size_t)(m0 + arow + srow) * K + schk;
  const ushort* Ag1 = A + (size_t)(m0 + arow + 16 + srow) * K + schk; // AI==2
  const ushort* Bg0 = B + (size_t)(n0 + brow + srow) * K + schk;
  const ushort* Bg1 = B + (size_t)(n0 + brow + 16 + srow) * K + schk; // BI==2
  const int lA0 = arow * 32, lA1 = (arow + 16) * 32;
  const int lB0 = brow * 32, lB1 = (brow + 16) * 32;

  // fragment offsets in the k-major layout: 16-row window = 512 shorts,
  // inside: [kchunk=quad][row=ln] 16B units.
  int aoff[MI], boff[NI];
#pragma unroll
  for (int i = 0; i < MI; i++)
    aoff[i] = (wm * (BM / 32) + i) * 512 + quad * 128 + ln * 8;
#pragma unroll
  for (int i = 0; i < NI; i++)
    boff[i] = (wn * (BN / 32) + i) * 512 + quad * 128 + ln * 8;
  f32x4 acc[MI][NI] = {};

  for (int kt = 0; kt < K; kt += 64) {
    __syncthreads();                        // WAR: prev rounds' reads done
    GLD_LDS16(Ag0 + kt, As0 + lA0);
    if (AI == 2) GLD_LDS16(Ag1 + kt, As0 + lA1);
    GLD_LDS16(Ag0 + kt + 32, As1 + lA0);
    if (AI == 2) GLD_LDS16(Ag1 + kt + 32, As1 + lA1);
    GLD_LDS16(Bg0 + kt, Bs0 + lB0);
    if (BI == 2) GLD_LDS16(Bg1 + kt, Bs0 + lB1);
    GLD_LDS16(Bg0 + kt + 32, Bs1 + lB0);
    if (BI == 2) GLD_LDS16(Bg1 + kt + 32, Bs1 + lB1);
    __syncthreads();                        // RAW: vmcnt drained at barrier
#pragma unroll
    for (int h = 0; h < 2; ++h) {
      const short* Ap = h ? As1 : As0;
      const short* Bp = h ? Bs1 : Bs0;
      short8 av[MI], bv[NI];
#pragma unroll
      for (int i = 0; i < MI; i++) av[i] = *(const short8*)&Ap[aoff[i]];
#pragma unroll
      for (int i = 0; i < NI; i++) bv[i] = *(const short8*)&Bp[boff[i]];
#pragma unroll
      for (int mi = 0; mi < MI; mi++)
#pragma unroll
        for (int ni = 0; ni < NI; ni++)
          acc[mi][ni] = MFMA16(av[mi], bv[ni], acc[mi][ni]);
    }
  }

  // Epilogue. C-layout: row = quad*4 + r, col = ln (verified m89/m91).
  if (MODE == 0) {
    ushort* Cq = (ushort*)Cv;
    if (n0 < 2048) {
      // ---- Q/K with fused RoPE ----
      ushort* dst = Cq + (n0 < 1024 ? 0 : 4194304);   // q or k buffer
      const int nbase = (n0 < 1024) ? n0 : n0 - 1024;
      const float qsc = (n0 < 1024) ? 0.04508422002778011f : 1.0f; // (1/32)*log2e
      const float sgn = (ln & 1) ? 1.0f : -1.0f;       // odd lane: +other*sn
      float invc[NI];                                  // invf * 1/(2*pi)
#pragma unroll
      for (int ni = 0; ni < NI; ni++) {
        // pair index within the head = (col & 63) >> 1, BN-generic
        const int ii = ((wn * (BN / 2) + ni * 16 + ln) & 63) >> 1;
        invc[ni] = __builtin_amdgcn_exp2f(-(float)ii * 0.4152410118579865f) *
                   0.15915494309189535f;
      }
#pragma unroll
      for (int mi = 0; mi < MI; mi++) {
        const int row = m0 + wm * (BM / 2) + mi * 16 + quad * 4;
#pragma unroll
        for (int ni = 0; ni < NI; ni++) {
          const int col = nbase + wn * (BN / 2) + ni * 16 + ln;
#pragma unroll
          for (int r = 0; r < 4; r++) {
            const float mine  = acc[mi][ni][r];
            const float other = __shfl_xor(mine, 1, 64);
            const int   s     = (row + r) & 2047;      // sequence position
            const float rev   = (float)s * invc[ni];
            const float rr    = rev - floorf(rev);
            const float sn = __builtin_amdgcn_sinf(rr);
            const float cs = __builtin_amdgcn_cosf(rr);
            const float rot = (mine * cs + sgn * other * sn) * qsc;
            dst[(size_t)(row + r) * 1024 + col] = f2bf(rot);
          }
        }
      }
    } else {
      // ---- V pre-transposed to [bh][d][s] (no rope) ----
      ushort* vt = Cq + 8388608;
#pragma unroll
      for (int mi = 0; mi < MI; mi++) {
        const int sm = m0 + wm * (BM / 2) + mi * 16 + quad * 4;  // token index
        const int b = sm >> 11, s = sm & 2047;
#pragma unroll
        for (int ni = 0; ni < NI; ni++) {
          const int nv = (n0 - 2048) + wn * (BN / 2) + ni * 16 + ln;
          const int bh = b * 16 + (nv >> 6), d = nv & 63;
          ushort4 u = make_ushort4(f2bf(acc[mi][ni][0]), f2bf(acc[mi][ni][1]),
                                   f2bf(acc[mi][ni][2]), f2bf(acc[mi][ni][3]));
          *(ushort4*)&vt[((size_t)bh * 64 + d) * 2048 + s] = u;
        }
      }
    }
  } else {
    float* C = (float*)Cv;
#pragma unroll
    for (int mi = 0; mi < MI; mi++) {
      const int row = m0 + wm * (BM / 2) + mi * 16 + quad * 4;
#pragma unroll
      for (int ni = 0; ni < NI; ni++) {
        const int col = n0 + wn * (BN / 2) + ni * 16 + ln;
#pragma unroll
        for (int r = 0; r < 4; r++)
          C[(size_t)(row + r) * 1024 + col] = acc[mi][ni][r];
      }
    }
  }
}

// ---------------------------------------------------------------------------
// Kernel 4 (r17-exact, REVERTED from r19's kv-half split which measured
// -1.9us): causal-balanced flash attention, max-free softmax. Block x in
// [0,16) owns q-tiles jA=x and jB=31-x. 512 thr = 8 waves: waves 0-3 own
// tile B's four 16-row groups, waves 4-7 own tile A's (r17: 2->4 waves/SIMD,
// measured 175.1 total — session best). A-waves idle-at-barrier for t>jA.
// r11: T14 reg prefetch. r13: swapped QK^T + cvt_pk pack + scalar l.
// ---------------------------------------------------------------------------
__global__ __launch_bounds__(512) void attnk(const ushort* __restrict__ q,
                                             const ushort* __restrict__ k,
                                             const ushort* __restrict__ vt,
                                             ushort* __restrict__ ctx) {
  __shared__ __align__(16) short Ks[2][64 * 72];
  __shared__ __align__(16) short Vs[2][64 * 72];
  __shared__ __align__(16) short Ps[8 * 16 * 72];
  const int tid  = threadIdx.x;
  const int lane = tid & 63, w = tid >> 6;          // w in [0,8)
  const int ln   = lane & 15, quad = lane >> 4;
  const int x = blockIdx.x, bh = blockIdx.y;
  const int b = bh >> 4, h = bh & 15;
  const int jA = x, jB = 31 - x;
  const int tile = w >> 2;                          // 0 = B (long), 1 = A
  const int wq   = w & 3;                           // 16-row group in tile
  const int j    = tile ? jA : jB;                  // my q-tile index
  short* Pw = Ps + w * 1152;

  // Q fragments for MY tile (per-lane layout: row=ln, k=quad*8+i)
  const size_t qb = ((size_t)(b * 2048 + j * 64 + wq * 16 + ln)) * 1024 + h * 64;
  const short8 aq0 = *(const short8*)&q[qb + quad * 8];
  const short8 aq1 = *(const short8*)&q[qb + 32 + quad * 8];

  f32x4 o[4] = {};
  float ls0 = 0.f, ls1 = 0.f;                       // per-lane l (q=ln)

  // staging: 512 threads cover the 64x64 tile as 512 short8 slots (1 each)
  const int r0 = tid >> 3, c0 = (tid & 7) * 8;
  const ushort* kg = k  + ((size_t)(b * 2048 + r0)) * 1024 + h * 64 + c0;
  const ushort* vg = vt + ((size_t)(bh * 64 + r0)) * 2048 + c0;
  const int wK = r0 * 72 + c0;

  // prologue: tile 0 -> regs -> buf0; tile 1 -> regs  (jB >= 16 always)
  short8 kr = *(const short8*)(kg);
  short8 vr = *(const short8*)(vg);
  *(short8*)&Ks[0][wK] = kr;
  *(short8*)&Vs[0][wK] = vr;
  kr = *(const short8*)(kg + 65536);
  vr = *(const short8*)(vg + 64);

  const int qloc = j * 64 + wq * 16 + ln;           // global q row (lane)

  for (int t = 0; t <= jB; t++) {
    // Invariant: buf[t&1] holds tile t; regs hold tile t+1.
    __syncthreads();   // barrier + lgkm drain (writes visible) + vmcnt drain
    const short* Kc = Ks[t & 1];
    const short* Vc = Vs[t & 1];
    if (t < jB) {      // stage tile t+1 into the other buffer
      *(short8*)&Ks[(t & 1) ^ 1][wK] = kr;
      *(short8*)&Vs[(t & 1) ^ 1][wK] = vr;
    }
    if (t + 2 <= jB) { // issue tile t+2 loads
      kr = *(const short8*)(kg + (size_t)(t + 2) * 65536);
      vr = *(const short8*)(vg + (t + 2) * 64);
    }

    const bool act = (tile == 0) || (t <= jA);      // wave-uniform
    if (act) {
      f32x4 sc[4];
#pragma unroll
      for (int ct = 0; ct < 4; ct++) {
        const short8 bk0 = *(const short8*)&Kc[(ct * 16 + ln) * 72 + quad * 8];
        const short8 bk1 = *(const short8*)&Kc[(ct * 16 + ln) * 72 + 32 + quad * 8];
        // SWAPPED operands: S^T = K.Q^T; lane holds S^T[kv=ct*16+quad*4+r][q=ln]
        f32x4 z = {0.f, 0.f, 0.f, 0.f};
        z = MFMA16(bk0, aq0, z);
        z = MFMA16(bk1, aq1, z);
        sc[ct] = z;
      }
      if (t == j) {                       // diag mask for my tile
#pragma unroll
        for (int ct = 0; ct < 4; ct++) {
          const int kvb = (t << 6) + ct * 16 + quad * 4;
#pragma unroll
          for (int r = 0; r < 4; r++)
            if (kvb + r > qloc) sc[ct][r] = -100000.0f;
        }
      }

      // V fragments
      short8 bv0[4], bv1[4];
#pragma unroll
      for (int dt = 0; dt < 4; dt++) {
        bv0[dt] = *(const short8*)&Vc[(dt * 16 + ln) * 72 + quad * 8];
        bv1[dt] = *(const short8*)&Vc[(dt * 16 + ln) * 72 + 32 + quad * 8];
      }

      // p = exp2(s'), pack 4 contiguous kv -> ds_write_b64
#pragma unroll
      for (int ct = 0; ct < 4; ct++) {
        const float p0 = __builtin_amdgcn_exp2f(sc[ct][0]);
        const float p1 = __builtin_amdgcn_exp2f(sc[ct][1]);
        const float p2 = __builtin_amdgcn_exp2f(sc[ct][2]);
        const float p3 = __builtin_amdgcn_exp2f(sc[ct][3]);
        ls0 += p0 + p1;
        ls1 += p2 + p3;
        const uint2 u = make_uint2(cvtpk_bf16(p0, p1), cvtpk_bf16(p2, p3));
        *(uint2*)&Pw[ln * 72 + ct * 16 + quad * 4] = u;
      }
      const short8 ap0 = *(const short8*)&Pw[ln * 72 + quad * 8];
      const short8 ap1 = *(const short8*)&Pw[ln * 72 + 32 + quad * 8];
#pragma unroll
      for (int dt = 0; dt < 4; dt++) {
        o[dt] = MFMA16(ap0, bv0[dt], o[dt]);
        o[dt] = MFMA16(ap1, bv1[dt], o[dt]);
      }
    }
  }

  // l total: lane holds partial for q=ln; sum across the 4 quads.
  float l = ls0 + ls1;
  l += __shfl_xor(l, 16, 64);
  l += __shfl_xor(l, 32, 64);

#pragma unroll
  for (int r = 0; r < 4; r++) {
    // O-frag rows are q-local = quad*4+r; l lives at lane ln'=quad*4+r.
    const float inv = 1.0f / __shfl(l, quad * 4 + r, 64);
    const int row = j * 64 + wq * 16 + quad * 4 + r;
#pragma unroll
    for (int dt = 0; dt < 4; dt++) {
      ctx[((size_t)(b * 2048 + row)) * 1024 + h * 64 + dt * 16 + ln] =
          f2bf(o[dt][r] * inv);
    }
  }
}

// ---------------------------------------------------------------------------
// Workspace: [xb 8MB][w bf16 8MB][qb 8MB][kb 8MB][vtb 8MB][ctx 8MB]
// ---------------------------------------------------------------------------
extern "C" void kernel_launch(void* const* d_in, const int* in_sizes, int n_in,
                              void* d_out, int out_size, void* d_ws, size_t ws_size,
                              hipStream_t stream) {
  const float* x  = (const float*)d_in[0];
  const float* Wq = (const float*)d_in[1];
  const float* Wk = (const float*)d_in[2];
  const float* Wv = (const float*)d_in[3];
  const float* Wo = (const float*)d_in[4];
  float* out = (float*)d_out;
  char* ws = (char*)d_ws;

  ushort* xb  = (ushort*)(ws);
  ushort* wqb = (ushort*)(ws + (size_t)(8  << 20));
  ushort* qb  = (ushort*)(ws + (size_t)(16 << 20));
  ushort* kb  = (ushort*)(ws + (size_t)(24 << 20));
  ushort* vtb = (ushort*)(ws + (size_t)(32 << 20));
  ushort* ctx = (ushort*)(ws + (size_t)(40 << 20));

  cvt_all<<<8192, 256, 0, stream>>>(x, Wq, Wk, Wv, Wo, xb);
  gemm_bt<0, 64, 128><<<dim3(48, 32), 256, 0, stream>>>(xb, wqb, (void*)qb, 1024);
  attnk<<<dim3(16, 32), 512, 0, stream>>>(qb, kb, vtb, ctx);
  gemm_bt<2, 64, 64><<<dim3(16, 64), 256, 0, stream>>>(ctx, wqb + 3145728 /*wob*/, (void*)out, 1024);
}

// Round 11
// 178.225 us; speedup vs baseline: 1.3102x; 1.3102x over previous
//
#include <hip/hip_runtime.h>

// ---------------------------------------------------------------------------
// CovariateAttention: out = MHA_causal(rope(x@Wq^T), rope(x@Wk^T), x@Wv^T) @ Wo^T
// B=2, S=2048, E=d_attn=1024, H=16, hd=64. All GEMM-shaped work in bf16 MFMA.
// 4 launches: cvt -> gemm0(QKV + fused RoPE) -> attnk(8-wave) -> gemm2.
// r21: r20 LDS-layout REVERTED (conflicts->0 but coalescing broke: 4 lanes/
// 64B-segment became 1 lane/segment = 4x transactions, 47->91us. The 4.7M
// b128 "conflict" count is benign — 8 touches/bank is the b128 floor, m134).
// gemm0 BM 128->64: residency 6->8 blocks/CU (wave-cap 32), the one lever
// with measured precedent here (MODE2 4/CU>2/CU; r14 6/CU>>3/CU).
// ---------------------------------------------------------------------------

typedef float  f32x4  __attribute__((ext_vector_type(4)));
typedef short  short8 __attribute__((ext_vector_type(8)));

#define MFMA16(a,b,c) __builtin_amdgcn_mfma_f32_16x16x32_bf16((a),(b),(c),0,0,0)
// async global->LDS DMA, 16B/lane; LDS dest = wave-uniform base + lane*16
#define GLD_LDS16(g, l)                                                        \
  __builtin_amdgcn_global_load_lds(                                            \
      (const __attribute__((address_space(1))) unsigned int*)(g),              \
      (__attribute__((address_space(3))) unsigned int*)(l), 16, 0, 0)

__device__ __forceinline__ unsigned short f2bf(float f) {
  unsigned int x = __float_as_uint(f);
  x += 0x7fffu + ((x >> 16) & 1u);          // RNE
  return (unsigned short)(x >> 16);
}
__device__ __forceinline__ float bf2f(unsigned short u) {
  return __uint_as_float(((unsigned int)u) << 16);
}
// packed f32x2 -> bf16x2 (RNE). No builtin on gfx950 (m240) -> inline asm.
__device__ __forceinline__ unsigned int cvtpk_bf16(float lo, float hi) {
  unsigned int r;
  asm("v_cvt_pk_bf16_f32 %0, %1, %2" : "=v"(r) : "v"(lo), "v"(hi));
  return r;
}

// ---------------------------------------------------------------------------
// Kernel 1: convert x (4M fp32) + Wq,Wk,Wv,Wo (1M each) to bf16 (contiguous).
// ---------------------------------------------------------------------------
__global__ __launch_bounds__(256) void cvt_all(const float* __restrict__ x,
                                               const float* __restrict__ wq,
                                               const float* __restrict__ wk,
                                               const float* __restrict__ wv,
                                               const float* __restrict__ wo,
                                               ushort* __restrict__ dst) {
  const int i = blockIdx.x * 256 + threadIdx.x;      // [0, 2M)
  const float* src;
  int off;
  if (i < 1048576) { src = x; off = i; }
  else {
    const int j = i - 1048576;
    const int wsel = j >> 18;
    off = j & 262143;
    src = (wsel == 0) ? wq : (wsel == 1) ? wk : (wsel == 2) ? wv : wo;
  }
  const float4 v = ((const float4*)src)[off];
  ushort4 o = make_ushort4(f2bf(v.x), f2bf(v.y), f2bf(v.z), f2bf(v.w));
  ((ushort4*)dst)[i] = o;
}

// ---------------------------------------------------------------------------
// GEMM (r9-exact K-loop + LDS layout, FROZEN: r10 dbuf / r14 128^2 /
// r15 phase-split / r16 split-K / r18 XCD-swizzle / r20 k-major-layout all
// regressed. Row-major [16rows][4x16B] windows, srow=lane>>2, schk=(lane&3)*8
// — 4 lanes per 64B global segment = coalesced; b128 read "conflicts" are
// the 8-touches/bank floor, benign.)
// C[m,n] = sum_k A[m,k]*B[n,k]. BM x BN tile, 256 thr = 4 waves (2x2),
// wave tile (BM/2) x (BN/2). BK=64 staged as TWO stride-32 panels via
// global_load_lds width=16; 2-barrier K-loop.
// MODE 0 (r21: BM=64, BN=64): fused QKV, N=3072, grid 48x64 = 3072 blocks
//   -> 8 blocks/CU resident (wave-cap 32/4; LDS 16KB caps at 10). Was 6/CU
//   at BM=128. Residency is the lever with measured precedent (see top).
// MODE 2 (BM=64, BN=64): fp32 out-proj, 1024 blocks = 4/CU.
// ---------------------------------------------------------------------------
template<int MODE, int BN, int BM>
__global__ __launch_bounds__(256) void gemm_bt(const ushort* __restrict__ A,
                                               const ushort* __restrict__ B,
                                               void* __restrict__ Cv,
                                               int K) {
  constexpr int NI = BN / 32;               // n-frags per wave
  constexpr int MI = BM / 32;               // m-frags per wave
  constexpr int AI = BM / 64;               // A staging instrs per wave/panel
  constexpr int BI = BN / 64;               // B staging instrs per wave/panel
  __shared__ __align__(16) short As0[BM * 32];
  __shared__ __align__(16) short As1[BM * 32];
  __shared__ __align__(16) short Bs0[BN * 32];
  __shared__ __align__(16) short Bs1[BN * 32];
  const int tid  = threadIdx.x;
  const int lane = tid & 63, w = tid >> 6;
  const int ln   = lane & 15, quad = lane >> 4;
  const int wm   = w >> 1, wn = w & 1;
  const int m0 = blockIdx.y * BM, n0 = blockIdx.x * BN;

  const int srow = lane >> 2;               // 0..15
  const int schk = (lane & 3) * 8;          // 0,8,16,24 (shorts)
  const int arow = w * (16 * AI);
  const int brow = w * (16 * BI);
  const ushort* Ag0 = A + (size_t)(m0 + arow + srow) * K + schk;
  const ushort* Ag1 = A + (size_t)(m0 + arow + 16 + srow) * K + schk; // AI==2
  const ushort* Bg0 = B + (size_t)(n0 + brow + srow) * K + schk;
  const ushort* Bg1 = B + (size_t)(n0 + brow + 16 + srow) * K + schk; // BI==2
  const int lA0 = arow * 32, lA1 = (arow + 16) * 32;
  const int lB0 = brow * 32, lB1 = (brow + 16) * 32;

  int aoff[MI], boff[NI];
#pragma unroll
  for (int i = 0; i < MI; i++)
    aoff[i] = (wm * (BM / 2) + i * 16 + ln) * 32 + quad * 8;
#pragma unroll
  for (int i = 0; i < NI; i++)
    boff[i] = (wn * (BN / 2) + i * 16 + ln) * 32 + quad * 8;
  f32x4 acc[MI][NI] = {};

  for (int kt = 0; kt < K; kt += 64) {
    __syncthreads();                        // WAR: prev rounds' reads done
    GLD_LDS16(Ag0 + kt, As0 + lA0);
    if (AI == 2) GLD_LDS16(Ag1 + kt, As0 + lA1);
    GLD_LDS16(Ag0 + kt + 32, As1 + lA0);
    if (AI == 2) GLD_LDS16(Ag1 + kt + 32, As1 + lA1);
    GLD_LDS16(Bg0 + kt, Bs0 + lB0);
    if (BI == 2) GLD_LDS16(Bg1 + kt, Bs0 + lB1);
    GLD_LDS16(Bg0 + kt + 32, Bs1 + lB0);
    if (BI == 2) GLD_LDS16(Bg1 + kt + 32, Bs1 + lB1);
    __syncthreads();                        // RAW: vmcnt drained at barrier
#pragma unroll
    for (int h = 0; h < 2; ++h) {
      const short* Ap = h ? As1 : As0;
      const short* Bp = h ? Bs1 : Bs0;
      short8 av[MI], bv[NI];
#pragma unroll
      for (int i = 0; i < MI; i++) av[i] = *(const short8*)&Ap[aoff[i]];
#pragma unroll
      for (int i = 0; i < NI; i++) bv[i] = *(const short8*)&Bp[boff[i]];
#pragma unroll
      for (int mi = 0; mi < MI; mi++)
#pragma unroll
        for (int ni = 0; ni < NI; ni++)
          acc[mi][ni] = MFMA16(av[mi], bv[ni], acc[mi][ni]);
    }
  }

  // Epilogue. C-layout: row = quad*4 + r, col = ln (verified m89/m91).
  if (MODE == 0) {
    ushort* Cq = (ushort*)Cv;
    if (n0 < 2048) {
      // ---- Q/K with fused RoPE ----
      ushort* dst = Cq + (n0 < 1024 ? 0 : 4194304);   // q or k buffer
      const int nbase = (n0 < 1024) ? n0 : n0 - 1024;
      const float qsc = (n0 < 1024) ? 0.04508422002778011f : 1.0f; // (1/32)*log2e
      const float sgn = (ln & 1) ? 1.0f : -1.0f;       // odd lane: +other*sn
      float invc[NI];                                  // invf * 1/(2*pi)
#pragma unroll
      for (int ni = 0; ni < NI; ni++) {
        // pair index within the head = (col & 63) >> 1, BN-generic
        const int ii = ((wn * (BN / 2) + ni * 16 + ln) & 63) >> 1;
        invc[ni] = __builtin_amdgcn_exp2f(-(float)ii * 0.4152410118579865f) *
                   0.15915494309189535f;
      }
#pragma unroll
      for (int mi = 0; mi < MI; mi++) {
        const int row = m0 + wm * (BM / 2) + mi * 16 + quad * 4;
#pragma unroll
        for (int ni = 0; ni < NI; ni++) {
          const int col = nbase + wn * (BN / 2) + ni * 16 + ln;
#pragma unroll
          for (int r = 0; r < 4; r++) {
            const float mine  = acc[mi][ni][r];
            const float other = __shfl_xor(mine, 1, 64);
            const int   s     = (row + r) & 2047;      // sequence position
            const float rev   = (float)s * invc[ni];
            const float rr    = rev - floorf(rev);
            const float sn = __builtin_amdgcn_sinf(rr);
            const float cs = __builtin_amdgcn_cosf(rr);
            const float rot = (mine * cs + sgn * other * sn) * qsc;
            dst[(size_t)(row + r) * 1024 + col] = f2bf(rot);
          }
        }
      }
    } else {
      // ---- V pre-transposed to [bh][d][s] (no rope) ----
      ushort* vt = Cq + 8388608;
#pragma unroll
      for (int mi = 0; mi < MI; mi++) {
        const int sm = m0 + wm * (BM / 2) + mi * 16 + quad * 4;  // token index
        const int b = sm >> 11, s = sm & 2047;
#pragma unroll
        for (int ni = 0; ni < NI; ni++) {
          const int nv = (n0 - 2048) + wn * (BN / 2) + ni * 16 + ln;
          const int bh = b * 16 + (nv >> 6), d = nv & 63;
          ushort4 u = make_ushort4(f2bf(acc[mi][ni][0]), f2bf(acc[mi][ni][1]),
                                   f2bf(acc[mi][ni][2]), f2bf(acc[mi][ni][3]));
          *(ushort4*)&vt[((size_t)bh * 64 + d) * 2048 + s] = u;
        }
      }
    }
  } else {
    float* C = (float*)Cv;
#pragma unroll
    for (int mi = 0; mi < MI; mi++) {
      const int row = m0 + wm * (BM / 2) + mi * 16 + quad * 4;
#pragma unroll
      for (int ni = 0; ni < NI; ni++) {
        const int col = n0 + wn * (BN / 2) + ni * 16 + ln;
#pragma unroll
        for (int r = 0; r < 4; r++)
          C[(size_t)(row + r) * 1024 + col] = acc[mi][ni][r];
      }
    }
  }
}

// ---------------------------------------------------------------------------
// Kernel 4 (r17-exact — session best, 175.1 total): causal-balanced flash
// attention, max-free softmax. Block x in [0,16) owns q-tiles jA=x and
// jB=31-x. 512 thr = 8 waves: waves 0-3 own tile B's four 16-row groups,
// waves 4-7 own tile A's (2->4 waves/SIMD). A-waves idle-at-barrier t>jA
// (r19's kv-half rebalance measured -1.9us — reverted).
// r11: T14 reg prefetch. r13: swapped QK^T + cvt_pk pack + scalar l.
// ---------------------------------------------------------------------------
__global__ __launch_bounds__(512) void attnk(const ushort* __restrict__ q,
                                             const ushort* __restrict__ k,
                                             const ushort* __restrict__ vt,
                                             ushort* __restrict__ ctx) {
  __shared__ __align__(16) short Ks[2][64 * 72];
  __shared__ __align__(16) short Vs[2][64 * 72];
  __shared__ __align__(16) short Ps[8 * 16 * 72];
  const int tid  = threadIdx.x;
  const int lane = tid & 63, w = tid >> 6;          // w in [0,8)
  const int ln   = lane & 15, quad = lane >> 4;
  const int x = blockIdx.x, bh = blockIdx.y;
  const int b = bh >> 4, h = bh & 15;
  const int jA = x, jB = 31 - x;
  const int tile = w >> 2;                          // 0 = B (long), 1 = A
  const int wq   = w & 3;                           // 16-row group in tile
  const int j    = tile ? jA : jB;                  // my q-tile index
  short* Pw = Ps + w * 1152;

  // Q fragments for MY tile (per-lane layout: row=ln, k=quad*8+i)
  const size_t qb = ((size_t)(b * 2048 + j * 64 + wq * 16 + ln)) * 1024 + h * 64;
  const short8 aq0 = *(const short8*)&q[qb + quad * 8];
  const short8 aq1 = *(const short8*)&q[qb + 32 + quad * 8];

  f32x4 o[4] = {};
  float ls0 = 0.f, ls1 = 0.f;                       // per-lane l (q=ln)

  // staging: 512 threads cover the 64x64 tile as 512 short8 slots (1 each)
  const int r0 = tid >> 3, c0 = (tid & 7) * 8;
  const ushort* kg = k  + ((size_t)(b * 2048 + r0)) * 1024 + h * 64 + c0;
  const ushort* vg = vt + ((size_t)(bh * 64 + r0)) * 2048 + c0;
  const int wK = r0 * 72 + c0;

  // prologue: tile 0 -> regs -> buf0; tile 1 -> regs  (jB >= 16 always)
  short8 kr = *(const short8*)(kg);
  short8 vr = *(const short8*)(vg);
  *(short8*)&Ks[0][wK] = kr;
  *(short8*)&Vs[0][wK] = vr;
  kr = *(const short8*)(kg + 65536);
  vr = *(const short8*)(vg + 64);

  const int qloc = j * 64 + wq * 16 + ln;           // global q row (lane)

  for (int t = 0; t <= jB; t++) {
    // Invariant: buf[t&1] holds tile t; regs hold tile t+1.
    __syncthreads();   // barrier + lgkm drain (writes visible) + vmcnt drain
    const short* Kc = Ks[t & 1];
    const short* Vc = Vs[t & 1];
    if (t < jB) {      // stage tile t+1 into the other buffer
      *(short8*)&Ks[(t & 1) ^ 1][wK] = kr;
      *(short8*)&Vs[(t & 1) ^ 1][wK] = vr;
    }
    if (t + 2 <= jB) { // issue tile t+2 loads
      kr = *(const short8*)(kg + (size_t)(t + 2) * 65536);
      vr = *(const short8*)(vg + (t + 2) * 64);
    }

    const bool act = (tile == 0) || (t <= jA);      // wave-uniform
    if (act) {
      f32x4 sc[4];
#pragma unroll
      for (int ct = 0; ct < 4; ct++) {
        const short8 bk0 = *(const short8*)&Kc[(ct * 16 + ln) * 72 + quad * 8];
        const short8 bk1 = *(const short8*)&Kc[(ct * 16 + ln) * 72 + 32 + quad * 8];
        // SWAPPED operands: S^T = K.Q^T; lane holds S^T[kv=ct*16+quad*4+r][q=ln]
        f32x4 z = {0.f, 0.f, 0.f, 0.f};
        z = MFMA16(bk0, aq0, z);
        z = MFMA16(bk1, aq1, z);
        sc[ct] = z;
      }
      if (t == j) {                       // diag mask for my tile
#pragma unroll
        for (int ct = 0; ct < 4; ct++) {
          const int kvb = (t << 6) + ct * 16 + quad * 4;
#pragma unroll
          for (int r = 0; r < 4; r++)
            if (kvb + r > qloc) sc[ct][r] = -100000.0f;
        }
      }

      // V fragments
      short8 bv0[4], bv1[4];
#pragma unroll
      for (int dt = 0; dt < 4; dt++) {
        bv0[dt] = *(const short8*)&Vc[(dt * 16 + ln) * 72 + quad * 8];
        bv1[dt] = *(const short8*)&Vc[(dt * 16 + ln) * 72 + 32 + quad * 8];
      }

      // p = exp2(s'), pack 4 contiguous kv -> ds_write_b64
#pragma unroll
      for (int ct = 0; ct < 4; ct++) {
        const float p0 = __builtin_amdgcn_exp2f(sc[ct][0]);
        const float p1 = __builtin_amdgcn_exp2f(sc[ct][1]);
        const float p2 = __builtin_amdgcn_exp2f(sc[ct][2]);
        const float p3 = __builtin_amdgcn_exp2f(sc[ct][3]);
        ls0 += p0 + p1;
        ls1 += p2 + p3;
        const uint2 u = make_uint2(cvtpk_bf16(p0, p1), cvtpk_bf16(p2, p3));
        *(uint2*)&Pw[ln * 72 + ct * 16 + quad * 4] = u;
      }
      const short8 ap0 = *(const short8*)&Pw[ln * 72 + quad * 8];
      const short8 ap1 = *(const short8*)&Pw[ln * 72 + 32 + quad * 8];
#pragma unroll
      for (int dt = 0; dt < 4; dt++) {
        o[dt] = MFMA16(ap0, bv0[dt], o[dt]);
        o[dt] = MFMA16(ap1, bv1[dt], o[dt]);
      }
    }
  }

  // l total: lane holds partial for q=ln; sum across the 4 quads.
  float l = ls0 + ls1;
  l += __shfl_xor(l, 16, 64);
  l += __shfl_xor(l, 32, 64);

#pragma unroll
  for (int r = 0; r < 4; r++) {
    // O-frag rows are q-local = quad*4+r; l lives at lane ln'=quad*4+r.
    const float inv = 1.0f / __shfl(l, quad * 4 + r, 64);
    const int row = j * 64 + wq * 16 + quad * 4 + r;
#pragma unroll
    for (int dt = 0; dt < 4; dt++) {
      ctx[((size_t)(b * 2048 + row)) * 1024 + h * 64 + dt * 16 + ln] =
          f2bf(o[dt][r] * inv);
    }
  }
}

// ---------------------------------------------------------------------------
// Workspace: [xb 8MB][w bf16 8MB][qb 8MB][kb 8MB][vtb 8MB][ctx 8MB]
// ---------------------------------------------------------------------------
extern "C" void kernel_launch(void* const* d_in, const int* in_sizes, int n_in,
                              void* d_out, int out_size, void* d_ws, size_t ws_size,
                              hipStream_t stream) {
  const float* x  = (const float*)d_in[0];
  const float* Wq = (const float*)d_in[1];
  const float* Wk = (const float*)d_in[2];
  const float* Wv = (const float*)d_in[3];
  const float* Wo = (const float*)d_in[4];
  float* out = (float*)d_out;
  char* ws = (char*)d_ws;

  ushort* xb  = (ushort*)(ws);
  ushort* wqb = (ushort*)(ws + (size_t)(8  << 20));
  ushort* qb  = (ushort*)(ws + (size_t)(16 << 20));
  ushort* kb  = (ushort*)(ws + (size_t)(24 << 20));
  ushort* vtb = (ushort*)(ws + (size_t)(32 << 20));
  ushort* ctx = (ushort*)(ws + (size_t)(40 << 20));

  cvt_all<<<8192, 256, 0, stream>>>(x, Wq, Wk, Wv, Wo, xb);
  gemm_bt<0, 64, 64><<<dim3(48, 64), 256, 0, stream>>>(xb, wqb, (void*)qb, 1024);
  attnk<<<dim3(16, 32), 512, 0, stream>>>(qb, kb, vtb, ctx);
  gemm_bt<2, 64, 64><<<dim3(16, 64), 256, 0, stream>>>(ctx, wqb + 3145728 /*wob*/, (void*)out, 1024);
}

// Round 12
// 173.343 us; speedup vs baseline: 1.3471x; 1.0282x over previous
//
#include <hip/hip_runtime.h>

// ---------------------------------------------------------------------------
// CovariateAttention: out = MHA_causal(rope(x@Wq^T), rope(x@Wk^T), x@Wv^T) @ Wo^T
// B=2, S=2048, E=d_attn=1024, H=16, hd=64. All GEMM-shaped work in bf16 MFMA.
// 4 launches: cvt -> gemm0(QKV + fused RoPE, BM=128) -> attnk(8-wave) -> gemm2.
// r22: FULL REVERT to R7-exact (session best, 175.1us) — r21's BM=64 raised
// occupancy 31->58% but regressed 47->49.4 (MFMA/barrier halved; residency
// curve flat past 6/CU). Plus ONE addition: T5 s_setprio around attnk's MFMA
// clusters (m191: +4-7% attn when blocks at different phases share a CU;
// attnk has 2 independent blocks/CU — the matching regime. m190's null was
// single-config lockstep GEMM, so gemm_bt is left untouched).
// ---------------------------------------------------------------------------

typedef float  f32x4  __attribute__((ext_vector_type(4)));
typedef short  short8 __attribute__((ext_vector_type(8)));

#define MFMA16(a,b,c) __builtin_amdgcn_mfma_f32_16x16x32_bf16((a),(b),(c),0,0,0)
// async global->LDS DMA, 16B/lane; LDS dest = wave-uniform base + lane*16
#define GLD_LDS16(g, l)                                                        \
  __builtin_amdgcn_global_load_lds(                                            \
      (const __attribute__((address_space(1))) unsigned int*)(g),              \
      (__attribute__((address_space(3))) unsigned int*)(l), 16, 0, 0)

__device__ __forceinline__ unsigned short f2bf(float f) {
  unsigned int x = __float_as_uint(f);
  x += 0x7fffu + ((x >> 16) & 1u);          // RNE
  return (unsigned short)(x >> 16);
}
__device__ __forceinline__ float bf2f(unsigned short u) {
  return __uint_as_float(((unsigned int)u) << 16);
}
// packed f32x2 -> bf16x2 (RNE). No builtin on gfx950 (m240) -> inline asm.
__device__ __forceinline__ unsigned int cvtpk_bf16(float lo, float hi) {
  unsigned int r;
  asm("v_cvt_pk_bf16_f32 %0, %1, %2" : "=v"(r) : "v"(lo), "v"(hi));
  return r;
}

// ---------------------------------------------------------------------------
// Kernel 1: convert x (4M fp32) + Wq,Wk,Wv,Wo (1M each) to bf16 (contiguous).
// ---------------------------------------------------------------------------
__global__ __launch_bounds__(256) void cvt_all(const float* __restrict__ x,
                                               const float* __restrict__ wq,
                                               const float* __restrict__ wk,
                                               const float* __restrict__ wv,
                                               const float* __restrict__ wo,
                                               ushort* __restrict__ dst) {
  const int i = blockIdx.x * 256 + threadIdx.x;      // [0, 2M)
  const float* src;
  int off;
  if (i < 1048576) { src = x; off = i; }
  else {
    const int j = i - 1048576;
    const int wsel = j >> 18;
    off = j & 262143;
    src = (wsel == 0) ? wq : (wsel == 1) ? wk : (wsel == 2) ? wv : wo;
  }
  const float4 v = ((const float4*)src)[off];
  ushort4 o = make_ushort4(f2bf(v.x), f2bf(v.y), f2bf(v.z), f2bf(v.w));
  ((ushort4*)dst)[i] = o;
}

// ---------------------------------------------------------------------------
// GEMM (r9-exact, FROZEN — the measured local optimum. Failed perturbations:
// r10 dbuf, r14 128^2 tile (3/CU), r15 phase-split (2x barriers), r16
// split-K (+11us net), r18 XCD swizzle (FETCH 38->54MB), r20 k-major LDS
// layout (coalescing broke, 2x slower; b128 "conflicts" are the benign
// 8-touches/bank floor), r21 BM=64 (occupancy up, MFMA/barrier down, -2.4us).
// At our shape (K=1024), 47us = 550 TF matches the m102 shape-curve for this
// structure; the path past it would need the full 8-phase counted-vmcnt
// template, whose only matching quadrant (128^2+8ph) measured NULL (m232).)
// C[m,n] = sum_k A[m,k]*B[n,k]. BM x BN tile, 256 thr = 4 waves (2x2),
// wave tile (BM/2) x (BN/2). BK=64 staged as TWO stride-32 panels via
// global_load_lds width=16; unpadded LDS stride 32; 2-barrier K-loop.
// MODE 0 (BM=128, BN=64): fused QKV, N=3072, 1536 blocks = 6/CU. Q/K get
//   RoPE in the epilogue. Q scaled by attn_scale*log2e. V -> [bh][d][s].
// MODE 2 (BM=64, BN=64): fp32 out-proj, 1024 blocks = 4/CU.
// ---------------------------------------------------------------------------
template<int MODE, int BN, int BM>
__global__ __launch_bounds__(256) void gemm_bt(const ushort* __restrict__ A,
                                               const ushort* __restrict__ B,
                                               void* __restrict__ Cv,
                                               int K) {
  constexpr int NI = BN / 32;               // n-frags per wave
  constexpr int MI = BM / 32;               // m-frags per wave
  constexpr int AI = BM / 64;               // A staging instrs per wave/panel
  constexpr int BI = BN / 64;               // B staging instrs per wave/panel
  __shared__ __align__(16) short As0[BM * 32];
  __shared__ __align__(16) short As1[BM * 32];
  __shared__ __align__(16) short Bs0[BN * 32];
  __shared__ __align__(16) short Bs1[BN * 32];
  const int tid  = threadIdx.x;
  const int lane = tid & 63, w = tid >> 6;
  const int ln   = lane & 15, quad = lane >> 4;
  const int wm   = w >> 1, wn = w & 1;
  const int m0 = blockIdx.y * BM, n0 = blockIdx.x * BN;

  const int srow = lane >> 2;               // 0..15
  const int schk = (lane & 3) * 8;          // 0,8,16,24 (shorts)
  const int arow = w * (16 * AI);
  const int brow = w * (16 * BI);
  const ushort* Ag0 = A + (size_t)(m0 + arow + srow) * K + schk;
  const ushort* Ag1 = A + (size_t)(m0 + arow + 16 + srow) * K + schk; // AI==2
  const ushort* Bg0 = B + (size_t)(n0 + brow + srow) * K + schk;
  const ushort* Bg1 = B + (size_t)(n0 + brow + 16 + srow) * K + schk; // BI==2
  const int lA0 = arow * 32, lA1 = (arow + 16) * 32;
  const int lB0 = brow * 32, lB1 = (brow + 16) * 32;

  int aoff[MI], boff[NI];
#pragma unroll
  for (int i = 0; i < MI; i++)
    aoff[i] = (wm * (BM / 2) + i * 16 + ln) * 32 + quad * 8;
#pragma unroll
  for (int i = 0; i < NI; i++)
    boff[i] = (wn * (BN / 2) + i * 16 + ln) * 32 + quad * 8;
  f32x4 acc[MI][NI] = {};

  for (int kt = 0; kt < K; kt += 64) {
    __syncthreads();                        // WAR: prev rounds' reads done
    GLD_LDS16(Ag0 + kt, As0 + lA0);
    if (AI == 2) GLD_LDS16(Ag1 + kt, As0 + lA1);
    GLD_LDS16(Ag0 + kt + 32, As1 + lA0);
    if (AI == 2) GLD_LDS16(Ag1 + kt + 32, As1 + lA1);
    GLD_LDS16(Bg0 + kt, Bs0 + lB0);
    if (BI == 2) GLD_LDS16(Bg1 + kt, Bs0 + lB1);
    GLD_LDS16(Bg0 + kt + 32, Bs1 + lB0);
    if (BI == 2) GLD_LDS16(Bg1 + kt + 32, Bs1 + lB1);
    __syncthreads();                        // RAW: vmcnt drained at barrier
#pragma unroll
    for (int h = 0; h < 2; ++h) {
      const short* Ap = h ? As1 : As0;
      const short* Bp = h ? Bs1 : Bs0;
      short8 av[MI], bv[NI];
#pragma unroll
      for (int i = 0; i < MI; i++) av[i] = *(const short8*)&Ap[aoff[i]];
#pragma unroll
      for (int i = 0; i < NI; i++) bv[i] = *(const short8*)&Bp[boff[i]];
#pragma unroll
      for (int mi = 0; mi < MI; mi++)
#pragma unroll
        for (int ni = 0; ni < NI; ni++)
          acc[mi][ni] = MFMA16(av[mi], bv[ni], acc[mi][ni]);
    }
  }

  // Epilogue. C-layout: row = quad*4 + r, col = ln (verified m89/m91).
  if (MODE == 0) {
    ushort* Cq = (ushort*)Cv;
    if (n0 < 2048) {
      // ---- Q/K with fused RoPE ----
      ushort* dst = Cq + (n0 < 1024 ? 0 : 4194304);   // q or k buffer
      const int nbase = (n0 < 1024) ? n0 : n0 - 1024;
      const float qsc = (n0 < 1024) ? 0.04508422002778011f : 1.0f; // (1/32)*log2e
      const float sgn = (ln & 1) ? 1.0f : -1.0f;       // odd lane: +other*sn
      float invc[NI];                                  // invf * 1/(2*pi)
#pragma unroll
      for (int ni = 0; ni < NI; ni++) {
        // pair index within the head = (col & 63) >> 1, BN-generic
        const int ii = ((wn * (BN / 2) + ni * 16 + ln) & 63) >> 1;
        invc[ni] = __builtin_amdgcn_exp2f(-(float)ii * 0.4152410118579865f) *
                   0.15915494309189535f;
      }
#pragma unroll
      for (int mi = 0; mi < MI; mi++) {
        const int row = m0 + wm * (BM / 2) + mi * 16 + quad * 4;
#pragma unroll
        for (int ni = 0; ni < NI; ni++) {
          const int col = nbase + wn * (BN / 2) + ni * 16 + ln;
#pragma unroll
          for (int r = 0; r < 4; r++) {
            const float mine  = acc[mi][ni][r];
            const float other = __shfl_xor(mine, 1, 64);
            const int   s     = (row + r) & 2047;      // sequence position
            const float rev   = (float)s * invc[ni];
            const float rr    = rev - floorf(rev);
            const float sn = __builtin_amdgcn_sinf(rr);
            const float cs = __builtin_amdgcn_cosf(rr);
            const float rot = (mine * cs + sgn * other * sn) * qsc;
            dst[(size_t)(row + r) * 1024 + col] = f2bf(rot);
          }
        }
      }
    } else {
      // ---- V pre-transposed to [bh][d][s] (no rope) ----
      ushort* vt = Cq + 8388608;
#pragma unroll
      for (int mi = 0; mi < MI; mi++) {
        const int sm = m0 + wm * (BM / 2) + mi * 16 + quad * 4;  // token index
        const int b = sm >> 11, s = sm & 2047;
#pragma unroll
        for (int ni = 0; ni < NI; ni++) {
          const int nv = (n0 - 2048) + wn * (BN / 2) + ni * 16 + ln;
          const int bh = b * 16 + (nv >> 6), d = nv & 63;
          ushort4 u = make_ushort4(f2bf(acc[mi][ni][0]), f2bf(acc[mi][ni][1]),
                                   f2bf(acc[mi][ni][2]), f2bf(acc[mi][ni][3]));
          *(ushort4*)&vt[((size_t)bh * 64 + d) * 2048 + s] = u;
        }
      }
    }
  } else {
    float* C = (float*)Cv;
#pragma unroll
    for (int mi = 0; mi < MI; mi++) {
      const int row = m0 + wm * (BM / 2) + mi * 16 + quad * 4;
#pragma unroll
      for (int ni = 0; ni < NI; ni++) {
        const int col = n0 + wn * (BN / 2) + ni * 16 + ln;
#pragma unroll
        for (int r = 0; r < 4; r++)
          C[(size_t)(row + r) * 1024 + col] = acc[mi][ni][r];
      }
    }
  }
}

// ---------------------------------------------------------------------------
// Kernel 4 (r17-exact structure + r22 setprio): causal-balanced flash
// attention, max-free softmax. Block x in [0,16) owns q-tiles jA=x and
// jB=31-x. 512 thr = 8 waves: waves 0-3 own tile B's four 16-row groups,
// waves 4-7 own tile A's (r17: 2->4 waves/SIMD, measured 175.1 total —
// session best). A-waves idle-at-barrier t>jA (r19 kv-half rebalance was
// -1.9us — reverted).
// r22: T5 s_setprio(1) around the two MFMA clusters — 2 blocks/CU at
// different loop phases give the CU scheduler something to arbitrate (m191
// regime, +4-7%); gemm left alone (m190: null for lockstep GEMM).
// r11: T14 reg prefetch. r13: swapped QK^T + cvt_pk pack + scalar l.
// ---------------------------------------------------------------------------
__global__ __launch_bounds__(512) void attnk(const ushort* __restrict__ q,
                                             const ushort* __restrict__ k,
                                             const ushort* __restrict__ vt,
                                             ushort* __restrict__ ctx) {
  __shared__ __align__(16) short Ks[2][64 * 72];
  __shared__ __align__(16) short Vs[2][64 * 72];
  __shared__ __align__(16) short Ps[8 * 16 * 72];
  const int tid  = threadIdx.x;
  const int lane = tid & 63, w = tid >> 6;          // w in [0,8)
  const int ln   = lane & 15, quad = lane >> 4;
  const int x = blockIdx.x, bh = blockIdx.y;
  const int b = bh >> 4, h = bh & 15;
  const int jA = x, jB = 31 - x;
  const int tile = w >> 2;                          // 0 = B (long), 1 = A
  const int wq   = w & 3;                           // 16-row group in tile
  const int j    = tile ? jA : jB;                  // my q-tile index
  short* Pw = Ps + w * 1152;

  // Q fragments for MY tile (per-lane layout: row=ln, k=quad*8+i)
  const size_t qb = ((size_t)(b * 2048 + j * 64 + wq * 16 + ln)) * 1024 + h * 64;
  const short8 aq0 = *(const short8*)&q[qb + quad * 8];
  const short8 aq1 = *(const short8*)&q[qb + 32 + quad * 8];

  f32x4 o[4] = {};
  float ls0 = 0.f, ls1 = 0.f;                       // per-lane l (q=ln)

  // staging: 512 threads cover the 64x64 tile as 512 short8 slots (1 each)
  const int r0 = tid >> 3, c0 = (tid & 7) * 8;
  const ushort* kg = k  + ((size_t)(b * 2048 + r0)) * 1024 + h * 64 + c0;
  const ushort* vg = vt + ((size_t)(bh * 64 + r0)) * 2048 + c0;
  const int wK = r0 * 72 + c0;

  // prologue: tile 0 -> regs -> buf0; tile 1 -> regs  (jB >= 16 always)
  short8 kr = *(const short8*)(kg);
  short8 vr = *(const short8*)(vg);
  *(short8*)&Ks[0][wK] = kr;
  *(short8*)&Vs[0][wK] = vr;
  kr = *(const short8*)(kg + 65536);
  vr = *(const short8*)(vg + 64);

  const int qloc = j * 64 + wq * 16 + ln;           // global q row (lane)

  for (int t = 0; t <= jB; t++) {
    // Invariant: buf[t&1] holds tile t; regs hold tile t+1.
    __syncthreads();   // barrier + lgkm drain (writes visible) + vmcnt drain
    const short* Kc = Ks[t & 1];
    const short* Vc = Vs[t & 1];
    if (t < jB) {      // stage tile t+1 into the other buffer
      *(short8*)&Ks[(t & 1) ^ 1][wK] = kr;
      *(short8*)&Vs[(t & 1) ^ 1][wK] = vr;
    }
    if (t + 2 <= jB) { // issue tile t+2 loads
      kr = *(const short8*)(kg + (size_t)(t + 2) * 65536);
      vr = *(const short8*)(vg + (t + 2) * 64);
    }

    const bool act = (tile == 0) || (t <= jA);      // wave-uniform
    if (act) {
      f32x4 sc[4];
      __builtin_amdgcn_s_setprio(1);                // T5: favor QK MFMA burst
#pragma unroll
      for (int ct = 0; ct < 4; ct++) {
        const short8 bk0 = *(const short8*)&Kc[(ct * 16 + ln) * 72 + quad * 8];
        const short8 bk1 = *(const short8*)&Kc[(ct * 16 + ln) * 72 + 32 + quad * 8];
        // SWAPPED operands: S^T = K.Q^T; lane holds S^T[kv=ct*16+quad*4+r][q=ln]
        f32x4 z = {0.f, 0.f, 0.f, 0.f};
        z = MFMA16(bk0, aq0, z);
        z = MFMA16(bk1, aq1, z);
        sc[ct] = z;
      }
      __builtin_amdgcn_s_setprio(0);
      if (t == j) {                       // diag mask for my tile
#pragma unroll
        for (int ct = 0; ct < 4; ct++) {
          const int kvb = (t << 6) + ct * 16 + quad * 4;
#pragma unroll
          for (int r = 0; r < 4; r++)
            if (kvb + r > qloc) sc[ct][r] = -100000.0f;
        }
      }

      // V fragments
      short8 bv0[4], bv1[4];
#pragma unroll
      for (int dt = 0; dt < 4; dt++) {
        bv0[dt] = *(const short8*)&Vc[(dt * 16 + ln) * 72 + quad * 8];
        bv1[dt] = *(const short8*)&Vc[(dt * 16 + ln) * 72 + 32 + quad * 8];
      }

      // p = exp2(s'), pack 4 contiguous kv -> ds_write_b64
#pragma unroll
      for (int ct = 0; ct < 4; ct++) {
        const float p0 = __builtin_amdgcn_exp2f(sc[ct][0]);
        const float p1 = __builtin_amdgcn_exp2f(sc[ct][1]);
        const float p2 = __builtin_amdgcn_exp2f(sc[ct][2]);
        const float p3 = __builtin_amdgcn_exp2f(sc[ct][3]);
        ls0 += p0 + p1;
        ls1 += p2 + p3;
        const uint2 u = make_uint2(cvtpk_bf16(p0, p1), cvtpk_bf16(p2, p3));
        *(uint2*)&Pw[ln * 72 + ct * 16 + quad * 4] = u;
      }
      const short8 ap0 = *(const short8*)&Pw[ln * 72 + quad * 8];
      const short8 ap1 = *(const short8*)&Pw[ln * 72 + 32 + quad * 8];
      __builtin_amdgcn_s_setprio(1);                // T5: favor PV MFMA burst
#pragma unroll
      for (int dt = 0; dt < 4; dt++) {
        o[dt] = MFMA16(ap0, bv0[dt], o[dt]);
        o[dt] = MFMA16(ap1, bv1[dt], o[dt]);
      }
      __builtin_amdgcn_s_setprio(0);
    }
  }

  // l total: lane holds partial for q=ln; sum across the 4 quads.
  float l = ls0 + ls1;
  l += __shfl_xor(l, 16, 64);
  l += __shfl_xor(l, 32, 64);

#pragma unroll
  for (int r = 0; r < 4; r++) {
    // O-frag rows are q-local = quad*4+r; l lives at lane ln'=quad*4+r.
    const float inv = 1.0f / __shfl(l, quad * 4 + r, 64);
    const int row = j * 64 + wq * 16 + quad * 4 + r;
#pragma unroll
    for (int dt = 0; dt < 4; dt++) {
      ctx[((size_t)(b * 2048 + row)) * 1024 + h * 64 + dt * 16 + ln] =
          f2bf(o[dt][r] * inv);
    }
  }
}

// ---------------------------------------------------------------------------
// Workspace: [xb 8MB][w bf16 8MB][qb 8MB][kb 8MB][vtb 8MB][ctx 8MB]
// ---------------------------------------------------------------------------
extern "C" void kernel_launch(void* const* d_in, const int* in_sizes, int n_in,
                              void* d_out, int out_size, void* d_ws, size_t ws_size,
                              hipStream_t stream) {
  const float* x  = (const float*)d_in[0];
  const float* Wq = (const float*)d_in[1];
  const float* Wk = (const float*)d_in[2];
  const float* Wv = (const float*)d_in[3];
  const float* Wo = (const float*)d_in[4];
  float* out = (float*)d_out;
  char* ws = (char*)d_ws;

  ushort* xb  = (ushort*)(ws);
  ushort* wqb = (ushort*)(ws + (size_t)(8  << 20));
  ushort* qb  = (ushort*)(ws + (size_t)(16 << 20));
  ushort* kb  = (ushort*)(ws + (size_t)(24 << 20));
  ushort* vtb = (ushort*)(ws + (size_t)(32 << 20));
  ushort* ctx = (ushort*)(ws + (size_t)(40 << 20));

  cvt_all<<<8192, 256, 0, stream>>>(x, Wq, Wk, Wv, Wo, xb);
  gemm_bt<0, 64, 128><<<dim3(48, 32), 256, 0, stream>>>(xb, wqb, (void*)qb, 1024);
  attnk<<<dim3(16, 32), 512, 0, stream>>>(qb, kb, vtb, ctx);
  gemm_bt<2, 64, 64><<<dim3(16, 64), 256, 0, stream>>>(ctx, wqb + 3145728 /*wob*/, (void*)out, 1024);
}